// Round 7
// baseline (158.414 us; speedup 1.0000x reference)
//
#include <hip/hip_runtime.h>

// RNNAdder round 6: r5 structure, TWO independent 16-seq groups per WG
// (grid 128 x 256). Each step runs group-A and group-B bodies back-to-back
// before ONE shared lgkmcnt-only barrier: each group's issue stream fills
// the other group's ds_read/MFMA/tanh latency (r5 was 730 cy/step stall
// with nothing to hide it). Weights/P/Wd/LUT fragments shared; separate
// hi/lo rings + token masks per group. Numerics bit-identical to r5.

typedef _Float16 half8 __attribute__((ext_vector_type(8)));
typedef float floatx4 __attribute__((ext_vector_type(4)));

#define MFMA16(A, B, C) __builtin_amdgcn_mfma_f32_16x16x32_f16((A), (B), (C), 0, 0, 0)
#define BARRIER() asm volatile("s_waitcnt lgkmcnt(0)\n\ts_barrier" ::: "memory")

// dword offsets: per-group block [HI 9216 | LO 1152 | NP 2080] = 12448 dw,
// two blocks, then shared one-hot LUT (1024 dw).
#define G_DW    12448
#define LO_DW   9216
#define NP_DW   10368
#define LUT_DW  (2 * G_DW)
#define POOL_DW (2 * G_DW + 1024)   // 25920 dw = 103.7 KB

__global__ __launch_bounds__(256)
void rnn_mfma(const int* __restrict__ num1, const int* __restrict__ num2,
              const float* __restrict__ E, const float* __restrict__ Wxh,
              const float* __restrict__ Whh, const float* __restrict__ bias,
              const float* __restrict__ Wd, const float* __restrict__ bd,
              float* __restrict__ out)
{
    __shared__ __align__(16) int pool[POOL_DW];
    _Float16* hiF  = (_Float16*)pool;
    int*      lutI = pool + LUT_DW;

    const int tid  = threadIdx.x;
    const int w    = tid >> 6;
    const int lane = tid & 63;
    const int c    = lane & 15;
    const int q    = lane >> 4;
    const int g    = blockIdx.x;     // 128 WGs x 32 seqs

    // ---- startup staging (overlaid on group-0 hi-ring, dwords 0..6015) ----
    float* WhhS = (float*)pool;
    float* P1t  = (float*)(pool + 4096);
    float* P2t  = (float*)(pool + 4736);
    float* WdS  = (float*)(pool + 5376);
    for (int i = tid; i < 4096; i += 256) WhhS[i] = Whh[i];
    for (int i = tid; i < 640;  i += 256) WdS[i]  = Wd[i];
    for (int idx = tid; idx < 640; idx += 256) {
        int v = idx >> 6, jj = idx & 63;
        float s1 = bias[jj], s2 = 0.f;
        #pragma unroll
        for (int i = 0; i < 32; ++i) {
            float e = E[v * 32 + i];
            s1 = fmaf(e, Wxh[i * 64 + jj], s1);
            s2 = fmaf(e, Wxh[(32 + i) * 64 + jj], s2);
        }
        P1t[idx] = s1;  // bias folded in
        P2t[idx] = s2;
    }
    {   // one-hot LUT: 256 entries x 4 dw
        int e = tid;
        #pragma unroll
        for (int j = 0; j < 4; ++j)
            lutI[e * 4 + j] = (((e >> (2 * j)) & 1) ? 0x3C00 : 0)
                            | (((e >> (2 * j + 1)) & 1) ? 0x3C000000 : 0);
    }
    // token bit-masks for both groups
    #pragma unroll
    for (int grp = 0; grp < 2; ++grp)
        for (int it = 0; it < 8; ++it) {
            int idx = it * 256 + tid;
            int m = idx & 15, t = idx >> 4;
            int s = g * 32 + grp * 16 + m;
            pool[grp * G_DW + NP_DW + t * 16 + m] =
                (1 << num1[s * 128 + t]) | (1 << (num2[s * 128 + t] + 10));
        }
    // zero ring slots read at t=0: hi slot 15, lo slot 1 (both groups)
    for (int i = tid; i < 576; i += 256) {
        pool[0 * G_DW + 15 * 576 + i]        = 0;
        pool[0 * G_DW + LO_DW + 576 + i]     = 0;
        pool[1 * G_DW + 15 * 576 + i]        = 0;
        pool[1 * G_DW + LO_DW + 576 + i]     = 0;
    }
    __syncthreads();

    // ---- B-fragments (shared by both groups) ----
    half8 Wf[2], Pf, Wdf[2];
    #pragma unroll
    for (int kt = 0; kt < 2; ++kt)
        #pragma unroll
        for (int j = 0; j < 8; ++j) {
            int k = kt * 32 + q * 8 + j;
            Wf[kt][j]  = (_Float16)WhhS[k * 64 + w * 16 + c];
            Wdf[kt][j] = (c < 10) ? (_Float16)WdS[k * 10 + c] : (_Float16)0.f;
        }
    #pragma unroll
    for (int j = 0; j < 8; ++j) {
        int i2 = q * 8 + j;
        float pv = (i2 < 10) ? P1t[i2 * 64 + w * 16 + c]
                 : (i2 < 20) ? P2t[(i2 - 10) * 64 + w * 16 + c] : 0.f;
        Pf[j] = (_Float16)pv;
    }
    float bdv = (c < 10) ? bd[c] : 0.f;
    __syncthreads();

    // ---- loop-invariant addresses (f16-element units) ----
    const int rvE = c * 72 + q * 8;
    const int wvE = (q * 4) * 72 + w * 16 + c;
    const int hi0 = 0,          lo0 = 2 * LO_DW;           // 0, 18432
    const int hi1 = 2 * G_DW,   lo1 = 2 * G_DW + 2 * LO_DW; // 24896, 43328
    const int* np0 = pool + NP_DW;
    const int* np1 = pool + G_DW + NP_DW;

    float* outP[2][2][4];
    #pragma unroll
    for (int grp = 0; grp < 2; ++grp)
        #pragma unroll
        for (int u = 0; u < 2; ++u)
            #pragma unroll
            for (int r = 0; r < 4; ++r)
                outP[grp][u][r] = out
                    + (((g * 32 + grp * 16 + q * 4 + r) * 128) + 2 * w + u) * 10 + c;

    const floatx4 zero4 = {0.f, 0.f, 0.f, 0.f};

    // ---- prologue: Cxp for t=0, both groups ----
    floatx4 Cxp0, Cxp1;
    {
        int mk = np0[c]; int mq = (mk >> (q * 8)) & 0xFF;
        half8 Aoh = *(const half8*)&lutI[mq * 4];
        Cxp0 = MFMA16(Aoh, Pf, zero4);
    }
    {
        int mk = np1[c]; int mq = (mk >> (q * 8)) & 0xFF;
        half8 Aoh = *(const half8*)&lutI[mq * 4];
        Cxp1 = MFMA16(Aoh, Pf, zero4);
    }

    for (int half = 0; half < 16; ++half) {
        const int sb  = (half & 1) * 8;      // write slot base
        const int npo = half * 128 + c;      // mask row base
        #pragma unroll
        for (int i = 0; i < 8; ++i) {
            // next-step token masks (off-chain)
            int mk0 = np0[npo + (i + 1) * 16];
            int mk1 = np1[npo + (i + 1) * 16];

            const int spw = sb + i;
            const int spr = (i == 0) ? ((sb ^ 8) + 7) : (sb + i - 1);
            const int lor = ((i + 1) & 1) * 1152;
            const int low = (i & 1) * 1152;

            // A-frag reads, both groups (direct b128, no perms)
            half8 A0h0 = *(const half8*)&hiF[hi0 + spr * 1152 + rvE];
            half8 A0h1 = *(const half8*)&hiF[hi0 + spr * 1152 + rvE + 32];
            half8 A0l0 = *(const half8*)&hiF[lo0 + lor + rvE];
            half8 A0l1 = *(const half8*)&hiF[lo0 + lor + rvE + 32];
            half8 A1h0 = *(const half8*)&hiF[hi1 + spr * 1152 + rvE];
            half8 A1h1 = *(const half8*)&hiF[hi1 + spr * 1152 + rvE + 32];
            half8 A1l0 = *(const half8*)&hiF[lo1 + lor + rvE];
            half8 A1l1 = *(const half8*)&hiF[lo1 + lor + rvE + 32];

            // recurrence MFMAs, both groups
            floatx4 C1a = MFMA16(A0h0, Wf[0], Cxp0);
            C1a         = MFMA16(A0h1, Wf[1], C1a);
            floatx4 C2a = MFMA16(A0l0, Wf[0], zero4);
            C2a         = MFMA16(A0l1, Wf[1], C2a);
            floatx4 C1b = MFMA16(A1h0, Wf[0], Cxp1);
            C1b         = MFMA16(A1h1, Wf[1], C1b);
            floatx4 C2b = MFMA16(A1l0, Wf[0], zero4);
            C2b         = MFMA16(A1l1, Wf[1], C2b);

            // next step's one-hot via LUT + xp MFMA
            {
                int mq = (mk0 >> (q * 8)) & 0xFF;
                half8 Aoh = *(const half8*)&lutI[mq * 4];
                Cxp0 = MFMA16(Aoh, Pf, zero4);
            }
            {
                int mq = (mk1 >> (q * 8)) & 0xFF;
                half8 Aoh = *(const half8*)&lutI[mq * 4];
                Cxp1 = MFMA16(Aoh, Pf, zero4);
            }

            // tanh + hi/lo split + writes, group 0 (value path = r5)
            #pragma unroll
            for (int r = 0; r < 4; ++r) {
                float x  = C1a[r] + C2a[r] * (1.f / 2048.f);
                float e2 = __builtin_amdgcn_exp2f(x * 2.885390081777927f);
                float hv = 1.f - 2.f * __builtin_amdgcn_rcpf(e2 + 1.f);
                _Float16 hh = (_Float16)hv;
                float hif = (float)hh;
                _Float16 hl = (_Float16)((hv - hif) * 2048.f);
                hiF[hi0 + spw * 1152 + wvE + r * 72] = hh;
                hiF[lo0 + low + wvE + r * 72] = hl;
            }
            // group 1
            #pragma unroll
            for (int r = 0; r < 4; ++r) {
                float x  = C1b[r] + C2b[r] * (1.f / 2048.f);
                float e2 = __builtin_amdgcn_exp2f(x * 2.885390081777927f);
                float hv = 1.f - 2.f * __builtin_amdgcn_rcpf(e2 + 1.f);
                _Float16 hh = (_Float16)hv;
                float hif = (float)hh;
                _Float16 hl = (_Float16)((hv - hif) * 2048.f);
                hiF[hi1 + spw * 1152 + wvE + r * 72] = hh;
                hiF[lo1 + low + wvE + r * 72] = hl;
            }

            // projection of steps (half-1)*8 .. +7 (slots published; lagged)
            if (i == 7 && half > 0) {
                const int sbp = (half & 1) ? 0 : 8;
                #pragma unroll
                for (int grp = 0; grp < 2; ++grp) {
                    const int gh = grp ? hi1 : hi0;
                    #pragma unroll
                    for (int u = 0; u < 2; ++u) {
                        const int pv = gh + (sbp + 2 * w + u) * 1152 + rvE;
                        half8 p0 = *(const half8*)&hiF[pv];
                        half8 p1 = *(const half8*)&hiF[pv + 32];
                        floatx4 Cp = MFMA16(p0, Wdf[0], zero4);
                        Cp         = MFMA16(p1, Wdf[1], Cp);
                        if (c < 10) {
                            #pragma unroll
                            for (int r = 0; r < 4; ++r)
                                outP[grp][u][r][-80] = Cp[r] + bdv;
                        }
                    }
                }
            }

            BARRIER();   // lgkmcnt-only: global stores stay in flight
        }
        #pragma unroll
        for (int grp = 0; grp < 2; ++grp)
            #pragma unroll
            for (int u = 0; u < 2; ++u)
                #pragma unroll
                for (int r = 0; r < 4; ++r)
                    outP[grp][u][r] += 80;   // +8 steps
    }

    // ---- epilogue: steps 120..127 (slots 8..15) ----
    #pragma unroll
    for (int grp = 0; grp < 2; ++grp) {
        const int gh = grp ? hi1 : hi0;
        #pragma unroll
        for (int u = 0; u < 2; ++u) {
            const int pv = gh + (8 + 2 * w + u) * 1152 + rvE;
            half8 p0 = *(const half8*)&hiF[pv];
            half8 p1 = *(const half8*)&hiF[pv + 32];
            floatx4 Cp = MFMA16(p0, Wdf[0], zero4);
            Cp         = MFMA16(p1, Wdf[1], Cp);
            if (c < 10) {
                #pragma unroll
                for (int r = 0; r < 4; ++r)
                    outP[grp][u][r][-80] = Cp[r] + bdv;
            }
        }
    }
}

extern "C" void kernel_launch(void* const* d_in, const int* in_sizes, int n_in,
                              void* d_out, int out_size, void* d_ws, size_t ws_size,
                              hipStream_t stream) {
    const int*   num1 = (const int*)d_in[0];
    const int*   num2 = (const int*)d_in[1];
    const float* E    = (const float*)d_in[2];
    const float* Wxh  = (const float*)d_in[3];
    const float* Whh  = (const float*)d_in[4];
    const float* b    = (const float*)d_in[5];
    const float* Wd   = (const float*)d_in[6];
    const float* bd   = (const float*)d_in[7];
    float* out = (float*)d_out;
    rnn_mfma<<<128, 256, 0, stream>>>(num1, num2, E, Wxh, Whh, b, Wd, bd, out);
}

// Round 8
// 139.506 us; speedup vs baseline: 1.1355x; 1.1355x over previous
//
#include <hip/hip_runtime.h>

// RNNAdder round 7: r5 body, TWO groups per WG in SEPARATE waves.
// 128 WGs x 512 threads: waves 0-3 = group A, waves 4-7 = group B, each wave
// runs the exact r5 per-wave body (68 VGPR) on its own group's LDS ring,
// sharing one lgkmcnt-only barrier. 2 waves/SIMD from independent groups
// hide each other's ds_read/MFMA/exp2 latency (r6 showed a single wave
// cannot overlap its own doubled body). Numerics bit-identical to r5.

typedef _Float16 half8 __attribute__((ext_vector_type(8)));
typedef float floatx4 __attribute__((ext_vector_type(4)));

#define MFMA16(A, B, C) __builtin_amdgcn_mfma_f32_16x16x32_f16((A), (B), (C), 0, 0, 0)
#define BARRIER() asm volatile("s_waitcnt lgkmcnt(0)\n\ts_barrier" ::: "memory")

// per-group block (dwords): HI ring 16x576 | LO 2x576 | NP 130x16
#define G_DW    12448
#define LO_DW   9216
#define NP_DW   10368
#define LUT_DW  (2 * G_DW)
#define POOL_DW (2 * G_DW + 1024)   // 25920 dw = 103.7 KB

__global__ __launch_bounds__(512)
void rnn_mfma(const int* __restrict__ num1, const int* __restrict__ num2,
              const float* __restrict__ E, const float* __restrict__ Wxh,
              const float* __restrict__ Whh, const float* __restrict__ bias,
              const float* __restrict__ Wd, const float* __restrict__ bd,
              float* __restrict__ out)
{
    __shared__ __align__(16) int pool[POOL_DW];
    _Float16* hiF  = (_Float16*)pool;
    int*      lutI = pool + LUT_DW;

    const int tid  = threadIdx.x;
    const int w8   = tid >> 6;
    const int grp  = w8 >> 2;        // group 0/1
    const int w    = w8 & 3;         // N-block within group
    const int lane = tid & 63;
    const int c    = lane & 15;
    const int q    = lane >> 4;
    const int g    = blockIdx.x;     // 128 WGs x 32 seqs

    // ---- startup staging (overlaid on group-0 hi-ring, dwords 0..6015) ----
    float* WhhS = (float*)pool;
    float* P1t  = (float*)(pool + 4096);
    float* P2t  = (float*)(pool + 4736);
    float* WdS  = (float*)(pool + 5376);
    for (int i = tid; i < 4096; i += 512) WhhS[i] = Whh[i];
    for (int i = tid; i < 640;  i += 512) WdS[i]  = Wd[i];
    for (int idx = tid; idx < 640; idx += 512) {
        int v = idx >> 6, jj = idx & 63;
        float s1 = bias[jj], s2 = 0.f;
        #pragma unroll
        for (int i = 0; i < 32; ++i) {
            float e = E[v * 32 + i];
            s1 = fmaf(e, Wxh[i * 64 + jj], s1);
            s2 = fmaf(e, Wxh[(32 + i) * 64 + jj], s2);
        }
        P1t[idx] = s1;  // bias folded in
        P2t[idx] = s2;
    }
    if (tid < 256) {   // one-hot LUT: 256 entries x 4 dw
        int e = tid;
        #pragma unroll
        for (int j = 0; j < 4; ++j)
            lutI[e * 4 + j] = (((e >> (2 * j)) & 1) ? 0x3C00 : 0)
                            | (((e >> (2 * j + 1)) & 1) ? 0x3C000000 : 0);
    }
    // token bit-masks, both groups
    for (int idx = tid; idx < 4096; idx += 512) {
        int gp = idx >> 11;
        int m = idx & 15, t = (idx >> 4) & 127;
        int s = g * 32 + gp * 16 + m;
        pool[gp * G_DW + NP_DW + t * 16 + m] =
            (1 << num1[s * 128 + t]) | (1 << (num2[s * 128 + t] + 10));
    }
    // zero ring slots read at t=0: hi slot 15, lo slot 1 (both groups)
    for (int i = tid; i < 576; i += 512) {
        pool[0 * G_DW + 15 * 576 + i]    = 0;
        pool[0 * G_DW + LO_DW + 576 + i] = 0;
        pool[1 * G_DW + 15 * 576 + i]    = 0;
        pool[1 * G_DW + LO_DW + 576 + i] = 0;
    }
    __syncthreads();

    // ---- B-fragments (same for every wave) ----
    half8 Wf[2], Pf, Wdf[2];
    #pragma unroll
    for (int kt = 0; kt < 2; ++kt)
        #pragma unroll
        for (int j = 0; j < 8; ++j) {
            int k = kt * 32 + q * 8 + j;
            Wf[kt][j]  = (_Float16)WhhS[k * 64 + w * 16 + c];
            Wdf[kt][j] = (c < 10) ? (_Float16)WdS[k * 10 + c] : (_Float16)0.f;
        }
    #pragma unroll
    for (int j = 0; j < 8; ++j) {
        int i2 = q * 8 + j;
        float pv = (i2 < 10) ? P1t[i2 * 64 + w * 16 + c]
                 : (i2 < 20) ? P2t[(i2 - 10) * 64 + w * 16 + c] : 0.f;
        Pf[j] = (_Float16)pv;
    }
    float bdv = (c < 10) ? bd[c] : 0.f;
    __syncthreads();   // staging region free for ring reuse after this

    // ---- loop-invariant addresses (f16-element units) ----
    const int rvE = c * 72 + q * 8;
    const int wvE = (q * 4) * 72 + w * 16 + c;
    const int hiE = grp * (2 * G_DW);        // group hi-ring base
    const int loE = hiE + 2 * LO_DW;         // group lo base
    const int* np = pool + grp * G_DW + NP_DW;

    float* outP[2][4];
    #pragma unroll
    for (int u = 0; u < 2; ++u)
        #pragma unroll
        for (int r = 0; r < 4; ++r)
            outP[u][r] = out
                + (((g * 32 + grp * 16 + q * 4 + r) * 128) + 2 * w + u) * 10 + c;

    const floatx4 zero4 = {0.f, 0.f, 0.f, 0.f};

    // ---- prologue: Cxp for t=0 ----
    floatx4 Cxp;
    {
        int mk = np[c];
        int mq = (mk >> (q * 8)) & 0xFF;
        half8 Aoh = *(const half8*)&lutI[mq * 4];
        Cxp = MFMA16(Aoh, Pf, zero4);
    }

    for (int half = 0; half < 16; ++half) {
        const int sb  = (half & 1) * 8;      // write slot base
        const int npo = half * 128 + c;
        #pragma unroll
        for (int i = 0; i < 8; ++i) {
            int mk = np[npo + (i + 1) * 16];   // next-step mask (off-chain)

            const int spw = sb + i;
            const int spr = (i == 0) ? ((sb ^ 8) + 7) : (sb + i - 1);
            const int lor = ((i + 1) & 1) * 1152;
            const int low = (i & 1) * 1152;

            // A-frags: direct b128 reads
            half8 Ah0 = *(const half8*)&hiF[hiE + spr * 1152 + rvE];
            half8 Ah1 = *(const half8*)&hiF[hiE + spr * 1152 + rvE + 32];
            half8 Al0 = *(const half8*)&hiF[loE + lor + rvE];
            half8 Al1 = *(const half8*)&hiF[loE + lor + rvE + 32];

            // recurrence (accumulation order = r5)
            floatx4 C1 = MFMA16(Ah0, Wf[0], Cxp);
            C1         = MFMA16(Ah1, Wf[1], C1);
            floatx4 C2 = MFMA16(Al0, Wf[0], zero4);
            C2         = MFMA16(Al1, Wf[1], C2);

            // next step's one-hot via LUT + xp MFMA
            {
                int mq = (mk >> (q * 8)) & 0xFF;
                half8 Aoh = *(const half8*)&lutI[mq * 4];
                Cxp = MFMA16(Aoh, Pf, zero4);
            }

            // tanh + hi/lo split, b16 writes (value path = r5)
            #pragma unroll
            for (int r = 0; r < 4; ++r) {
                float x  = C1[r] + C2[r] * (1.f / 2048.f);
                float e2 = __builtin_amdgcn_exp2f(x * 2.885390081777927f);
                float hv = 1.f - 2.f * __builtin_amdgcn_rcpf(e2 + 1.f);
                _Float16 hh = (_Float16)hv;
                float hif = (float)hh;
                _Float16 hl = (_Float16)((hv - hif) * 2048.f);
                hiF[hiE + spw * 1152 + wvE + r * 72] = hh;
                hiF[loE + low + wvE + r * 72] = hl;
            }

            // projection of previous half's steps (slots already published)
            if (i == 7 && half > 0) {
                const int sbp = (half & 1) ? 0 : 8;
                #pragma unroll
                for (int u = 0; u < 2; ++u) {
                    const int pv = hiE + (sbp + 2 * w + u) * 1152 + rvE;
                    half8 p0 = *(const half8*)&hiF[pv];
                    half8 p1 = *(const half8*)&hiF[pv + 32];
                    floatx4 Cp = MFMA16(p0, Wdf[0], zero4);
                    Cp         = MFMA16(p1, Wdf[1], Cp);
                    if (c < 10) {
                        #pragma unroll
                        for (int r = 0; r < 4; ++r)
                            outP[u][r][-80] = Cp[r] + bdv;
                    }
                }
            }

            BARRIER();   // lgkmcnt-only: global stores stay in flight
        }
        #pragma unroll
        for (int u = 0; u < 2; ++u)
            #pragma unroll
            for (int r = 0; r < 4; ++r)
                outP[u][r] += 80;   // +8 steps
    }

    // ---- epilogue: steps 120..127 (slots 8..15) ----
    #pragma unroll
    for (int u = 0; u < 2; ++u) {
        const int pv = hiE + (8 + 2 * w + u) * 1152 + rvE;
        half8 p0 = *(const half8*)&hiF[pv];
        half8 p1 = *(const half8*)&hiF[pv + 32];
        floatx4 Cp = MFMA16(p0, Wdf[0], zero4);
        Cp         = MFMA16(p1, Wdf[1], Cp);
        if (c < 10) {
            #pragma unroll
            for (int r = 0; r < 4; ++r)
                outP[u][r][-80] = Cp[r] + bdv;
        }
    }
}

extern "C" void kernel_launch(void* const* d_in, const int* in_sizes, int n_in,
                              void* d_out, int out_size, void* d_ws, size_t ws_size,
                              hipStream_t stream) {
    const int*   num1 = (const int*)d_in[0];
    const int*   num2 = (const int*)d_in[1];
    const float* E    = (const float*)d_in[2];
    const float* Wxh  = (const float*)d_in[3];
    const float* Whh  = (const float*)d_in[4];
    const float* b    = (const float*)d_in[5];
    const float* Wd   = (const float*)d_in[6];
    const float* bd   = (const float*)d_in[7];
    float* out = (float*)d_out;
    rnn_mfma<<<128, 512, 0, stream>>>(num1, num2, E, Wxh, Whh, b, Wd, bd, out);
}

// Round 9
// 119.850 us; speedup vs baseline: 1.3218x; 1.1640x over previous
//
#include <hip/hip_runtime.h>

// RNNAdder round 8: r5 skeleton (256 WG x 256 thr, 4 waves, 16-slot ring,
// LUT one-hot, lgkm-only barrier) with a packed-pair ring:
//  (a) ring element = (h_hi f16 | h_lo*64 f16) in one dword; recurrence MFMAs
//      use interleaved B = [W[k], W[k]/64,...] so hi+lo accumulate in the
//      SAME 5 MFMAs (Ca/Cb split keeps the 2-deep chain). Writes 8b16->4b32,
//      lo ring gone, x = Ca+Cb (no /2048 fma).
//  (b) projection spread: u=0 at i==2, u=1 at i==6 (kills the i==7 burst);
//      projection uses packed frags + [Wd, Wd/64] B -> hi+lo accurate.
//  (c) np mask read first after barrier (fills A-read shadow with LUT/xp).

typedef _Float16 half8 __attribute__((ext_vector_type(8)));
typedef __fp16 fp16x2 __attribute__((ext_vector_type(2)));
typedef float floatx4 __attribute__((ext_vector_type(4)));

#define MFMA16(A, B, C) __builtin_amdgcn_mfma_f32_16x16x32_f16((A), (B), (C), 0, 0, 0)
#define BARRIER() asm volatile("s_waitcnt lgkmcnt(0)\n\ts_barrier" ::: "memory")

// pool dword layout
#define LUT_DW  17408                 // ring: 16 slots x 16 rows x 68 dw
#define NP_DW   18432                 // 130 rows x 16
#define POOL_DW 20512                 // 82 KB

__global__ __launch_bounds__(256)
void rnn_mfma(const int* __restrict__ num1, const int* __restrict__ num2,
              const float* __restrict__ E, const float* __restrict__ Wxh,
              const float* __restrict__ Whh, const float* __restrict__ bias,
              const float* __restrict__ Wd, const float* __restrict__ bd,
              float* __restrict__ out)
{
    __shared__ __align__(16) int pool[POOL_DW];
    int* lutI  = pool + LUT_DW;
    int* numpk = pool + NP_DW;

    const int tid  = threadIdx.x;
    const int w    = tid >> 6;
    const int lane = tid & 63;
    const int c    = lane & 15;
    const int q    = lane >> 4;
    const int g    = blockIdx.x;

    // ---- startup staging (overlaid on ring slots 0..5) ----
    float* WhhS = (float*)pool;           // 4096
    float* P1t  = (float*)(pool + 4096);  // 640
    float* P2t  = (float*)(pool + 4736);  // 640
    float* WdS  = (float*)(pool + 5376);  // 640
    for (int i = tid; i < 4096; i += 256) WhhS[i] = Whh[i];
    for (int i = tid; i < 640;  i += 256) WdS[i]  = Wd[i];
    for (int idx = tid; idx < 640; idx += 256) {
        int v = idx >> 6, jj = idx & 63;
        float s1 = bias[jj], s2 = 0.f;
        #pragma unroll
        for (int i = 0; i < 32; ++i) {
            float e = E[v * 32 + i];
            s1 = fmaf(e, Wxh[i * 64 + jj], s1);
            s2 = fmaf(e, Wxh[(32 + i) * 64 + jj], s2);
        }
        P1t[idx] = s1;  // bias folded in
        P2t[idx] = s2;
    }
    {   // one-hot LUT: 256 entries x 4 dw
        int e = tid;
        #pragma unroll
        for (int j = 0; j < 4; ++j)
            lutI[e * 4 + j] = (((e >> (2 * j)) & 1) ? 0x3C00 : 0)
                            | (((e >> (2 * j + 1)) & 1) ? 0x3C000000 : 0);
    }
    // token bit-masks (rows 128..129 zero-padded)
    for (int idx = tid; idx < 2080; idx += 256) {
        int m = idx & 15, t = idx >> 4;
        int s = g * 16 + m;
        numpk[t * 16 + m] = (t < 128)
            ? ((1 << num1[s * 128 + t]) | (1 << (num2[s * 128 + t] + 10))) : 0;
    }
    __syncthreads();

    // ---- resident B-fragments ----
    // interleaved Whh: Wint[kt][2p] = W[kt*16+q*4+p][n], [2p+1] = same/64
    half8 Wint[4], Wdint[4], Pf;
    #pragma unroll
    for (int kt = 0; kt < 4; ++kt)
        #pragma unroll
        for (int p = 0; p < 4; ++p) {
            int k = kt * 16 + q * 4 + p;
            float wv = WhhS[k * 64 + w * 16 + c];
            Wint[kt][2 * p]     = (_Float16)wv;
            Wint[kt][2 * p + 1] = (_Float16)(wv * 0.015625f);
            float dv = (c < 10) ? WdS[k * 10 + c] : 0.f;
            Wdint[kt][2 * p]     = (_Float16)dv;
            Wdint[kt][2 * p + 1] = (_Float16)(dv * 0.015625f);
        }
    #pragma unroll
    for (int j = 0; j < 8; ++j) {   // Pf keeps the old k = q*8+j mapping
        int i2 = q * 8 + j;
        float pv = (i2 < 10) ? P1t[i2 * 64 + w * 16 + c]
                 : (i2 < 20) ? P2t[(i2 - 10) * 64 + w * 16 + c] : 0.f;
        Pf[j] = (_Float16)pv;
    }
    float bdv = (c < 10) ? bd[c] : 0.f;
    __syncthreads();   // staging region free for ring reuse

    // ---- zero slot 15 (h_{-1}=0) ----
    for (int i = tid; i < 1088; i += 256) pool[15 * 1088 + i] = 0;
    __syncthreads();

    // ---- loop-invariant addresses (dword units) ----
    const int rBase = c * 68 + q * 4;                 // A-read row c, kt*16 tiles
    const int wBase = (q * 4) * 68 + w * 16 + c;      // write rows q*4+r

    float* outP[2][4];
    #pragma unroll
    for (int u = 0; u < 2; ++u)
        #pragma unroll
        for (int r = 0; r < 4; ++r)
            outP[u][r] = out + (((g * 16 + q * 4 + r) * 128) + 2 * w + u) * 10 + c;

    const floatx4 zero4 = {0.f, 0.f, 0.f, 0.f};

    // ---- prologue: Cxp for t=0 ----
    floatx4 Cxp;
    {
        int mk = numpk[c];
        int mq = (mk >> (q * 8)) & 0xFF;
        half8 Aoh = *(const half8*)&lutI[mq * 4];
        Cxp = MFMA16(Aoh, Pf, zero4);
    }

    for (int half = 0; half < 16; ++half) {
        const int sb  = (half & 1) * 8;
        const int npo = half * 128 + c;
        #pragma unroll
        for (int i = 0; i < 8; ++i) {
            // next-step token mask first: fills the A-read shadow
            int mk = numpk[npo + (i + 1) * 16];

            const int spw = sb + i;
            const int spr = (i == 0) ? ((sb ^ 8) + 7) : (sb + i - 1);

            // packed A-frags: 4 x b128
            half8 A0 = *(const half8*)&pool[spr * 1088 + rBase];
            half8 A1 = *(const half8*)&pool[spr * 1088 + rBase + 16];
            half8 A2 = *(const half8*)&pool[spr * 1088 + rBase + 32];
            half8 A3 = *(const half8*)&pool[spr * 1088 + rBase + 48];

            // recurrence: hi+lo fused, 2-deep chains
            floatx4 Ca = MFMA16(A0, Wint[0], Cxp);
            Ca         = MFMA16(A1, Wint[1], Ca);
            floatx4 Cb = MFMA16(A2, Wint[2], zero4);
            Cb         = MFMA16(A3, Wint[3], Cb);

            // next step's one-hot + xp (independent)
            {
                int mq = (mk >> (q * 8)) & 0xFF;
                half8 Aoh = *(const half8*)&lutI[mq * 4];
                Cxp = MFMA16(Aoh, Pf, zero4);
            }

            // tanh + pack (hi RTZ f16 | residual*64 f16) + 4 b32 writes
            float hv[4];
            #pragma unroll
            for (int r = 0; r < 4; ++r) {
                float x  = Ca[r] + Cb[r];
                float e2 = __builtin_amdgcn_exp2f(x * 2.885390081777927f);
                hv[r] = 1.f - 2.f * __builtin_amdgcn_rcpf(e2 + 1.f);
            }
            #pragma unroll
            for (int p = 0; p < 2; ++p) {
                fp16x2 ph = __builtin_amdgcn_cvt_pkrtz(hv[2 * p], hv[2 * p + 1]);
                float c0 = (float)ph[0];
                float c1 = (float)ph[1];
                fp16x2 pl = __builtin_amdgcn_cvt_pkrtz((hv[2 * p] - c0) * 64.f,
                                                       (hv[2 * p + 1] - c1) * 64.f);
                unsigned phu = __builtin_bit_cast(unsigned, ph);
                unsigned plu = __builtin_bit_cast(unsigned, pl);
                unsigned w0 = __builtin_amdgcn_perm(plu, phu, 0x05040100u);
                unsigned w1 = __builtin_amdgcn_perm(plu, phu, 0x07060302u);
                pool[spw * 1088 + wBase + (2 * p) * 68]     = (int)w0;
                pool[spw * 1088 + wBase + (2 * p + 1) * 68] = (int)w1;
            }

            // spread projection: u=0 at i==2, u=1 at i==6 (prev half's slots)
            if ((i == 2 || i == 6) && half > 0) {
                const int u   = (i == 6);
                const int sbp = (half & 1) ? 0 : 8;
                const int sl  = (sbp + 2 * w + u) * 1088 + rBase;
                half8 P0 = *(const half8*)&pool[sl];
                half8 P1 = *(const half8*)&pool[sl + 16];
                half8 P2 = *(const half8*)&pool[sl + 32];
                half8 P3 = *(const half8*)&pool[sl + 48];
                floatx4 Cp = MFMA16(P0, Wdint[0], zero4);
                Cp         = MFMA16(P1, Wdint[1], Cp);
                Cp         = MFMA16(P2, Wdint[2], Cp);
                Cp         = MFMA16(P3, Wdint[3], Cp);
                if (c < 10) {
                    #pragma unroll
                    for (int r = 0; r < 4; ++r)
                        outP[u][r][-80] = Cp[r] + bdv;
                }
            }

            BARRIER();   // lgkmcnt-only: global stores stay in flight
        }
        #pragma unroll
        for (int u = 0; u < 2; ++u)
            #pragma unroll
            for (int r = 0; r < 4; ++r)
                outP[u][r] += 80;   // +8 steps
    }

    // ---- epilogue: steps 120..127 (slots 8..15) ----
    #pragma unroll
    for (int u = 0; u < 2; ++u) {
        const int sl = (8 + 2 * w + u) * 1088 + rBase;
        half8 P0 = *(const half8*)&pool[sl];
        half8 P1 = *(const half8*)&pool[sl + 16];
        half8 P2 = *(const half8*)&pool[sl + 32];
        half8 P3 = *(const half8*)&pool[sl + 48];
        floatx4 Cp = MFMA16(P0, Wdint[0], zero4);
        Cp         = MFMA16(P1, Wdint[1], Cp);
        Cp         = MFMA16(P2, Wdint[2], Cp);
        Cp         = MFMA16(P3, Wdint[3], Cp);
        if (c < 10) {
            #pragma unroll
            for (int r = 0; r < 4; ++r)
                outP[u][r][-80] = Cp[r] + bdv;
        }
    }
}

extern "C" void kernel_launch(void* const* d_in, const int* in_sizes, int n_in,
                              void* d_out, int out_size, void* d_ws, size_t ws_size,
                              hipStream_t stream) {
    const int*   num1 = (const int*)d_in[0];
    const int*   num2 = (const int*)d_in[1];
    const float* E    = (const float*)d_in[2];
    const float* Wxh  = (const float*)d_in[3];
    const float* Whh  = (const float*)d_in[4];
    const float* b    = (const float*)d_in[5];
    const float* Wd   = (const float*)d_in[6];
    const float* bd   = (const float*)d_in[7];
    float* out = (float*)d_out;
    rnn_mfma<<<256, 256, 0, stream>>>(num1, num2, E, Wxh, Whh, b, Wd, bd, out);
}